// Round 1
// baseline (773.596 us; speedup 1.0000x reference)
//
#include <hip/hip_runtime.h>

#define NB 16
#define NN 1024
#define ND 128
#define NDP 129
#define NK 128
#define BND (NB*NN)
#define SQRTK 11.313708498984761f

__device__ __forceinline__ float artanh_clip(float x){
  x = fminf(fmaxf(x, -1.0f+1e-5f), 1.0f-1e-5f);
  return 0.5f*logf((1.0f+x)/(1.0f-x));
}

__device__ __forceinline__ float bsum128(float v, volatile float* red){
  #pragma unroll
  for (int o=32;o>0;o>>=1) v += __shfl_down(v,o,64);
  int t = threadIdx.x;
  __syncthreads();
  if ((t&63)==0) red[t>>6] = v;
  __syncthreads();
  return red[0]+red[1];
}

// ---------------- K1: p2l for sentence and comment reps ----------------
__global__ void k_p2l(const float* __restrict__ s, const float* __restrict__ c,
                      float* __restrict__ ls, float* __restrict__ lc){
  __shared__ float red[2];
  int row = blockIdx.x;
  const float* in; float* out;
  if (row < BND){ in = s + (size_t)row*ND; out = ls + (size_t)row*NDP; }
  else { row -= BND; in = c + (size_t)row*ND; out = lc + (size_t)row*NDP; }
  int t = threadIdx.x; // 128
  float x = in[t];
  float v = x*x;
  #pragma unroll
  for (int o=32;o>0;o>>=1) v += __shfl_down(v,o,64);
  if ((t&63)==0) red[t>>6] = v;
  __syncthreads();
  float x2 = red[0]+red[1];
  float inv = SQRTK / (1.0f - x2 + 1e-6f);
  if (t==0) out[0] = (1.0f+x2)*inv;
  out[1+t] = 2.0f*x*inv;
}

// ---------------- K2a: Y = X @ W^T (j = 0..127; j=128 handled in K2b) ----------------
__global__ void k_lin_gemm(const float* __restrict__ ls, const float* __restrict__ lc,
    const float* __restrict__ Wl,const float* __restrict__ Ws,const float* __restrict__ Wc,
    const float* __restrict__ bl,const float* __restrict__ bs,const float* __restrict__ bc,
    float* __restrict__ Y){
  __shared__ __align__(16) float As_[64][68];
  __shared__ __align__(16) float Bs_[64][68];
  int which = blockIdx.z;
  const float* X = (which==1)? ls : lc;
  const float* W = (which==0)? Wl : (which==1? Ws : Wc);
  const float* bias = (which==0)? bl : (which==1? bs : bc);
  float* Yw = Y + (size_t)which*BND*NDP;
  int r0 = blockIdx.x*64;
  int j0 = blockIdx.y*64;
  int t = threadIdx.x;
  int tr = t>>4, tc = t&15;
  float acc[4][4] = {};
  for (int half=0; half<2; ++half){
    int d0 = half*68;
    __syncthreads();
    for (int i=t; i<64*68; i+=256){
      int r = i/68, d = i%68;
      float v = 0.f;
      if (d0+d < NDP) v = X[(size_t)(r0+r)*NDP + d0+d];
      As_[r][d] = v;
    }
    for (int i=t; i<64*68; i+=256){
      int r = i/68, d = i%68;
      float v = 0.f;
      if (d0+d < NDP) v = W[(size_t)(j0+r)*NDP + d0+d];
      Bs_[r][d] = v;
    }
    __syncthreads();
    for (int kk=0; kk<68; kk+=4){
      float4 a[4], b4[4];
      #pragma unroll
      for (int i=0;i<4;i++) a[i] = *(const float4*)&As_[tr*4+i][kk];
      #pragma unroll
      for (int q=0;q<4;q++) b4[q] = *(const float4*)&Bs_[tc+16*q][kk];
      #pragma unroll
      for (int i=0;i<4;i++)
        #pragma unroll
        for (int q=0;q<4;q++)
          acc[i][q] += a[i].x*b4[q].x + a[i].y*b4[q].y + a[i].z*b4[q].z + a[i].w*b4[q].w;
    }
  }
  #pragma unroll
  for (int i=0;i<4;i++){
    int r = r0 + tr*4 + i;
    #pragma unroll
    for (int q=0;q<4;q++){
      int j = j0 + tc + 16*q;
      Yw[(size_t)r*NDP + j] = acc[i][q] + bias[j];
    }
  }
}

// ---------------- K2b: lorentz_linear nonlinearity (+ y128) ----------------
__global__ void k_lin_post(const float* __restrict__ ls, const float* __restrict__ lc,
    const float* __restrict__ Wl,const float* __restrict__ Ws,const float* __restrict__ Wc,
    const float* __restrict__ bl,const float* __restrict__ bs,const float* __restrict__ bc,
    const float* __restrict__ scl,const float* __restrict__ scs,const float* __restrict__ scc,
    const float* __restrict__ Y,
    float* __restrict__ Lw, float* __restrict__ Ps, float* __restrict__ Pc){
  __shared__ float red[2];
  __shared__ float sh_y0;
  int blk = blockIdx.x;
  int which = blk >> 14;
  int row = blk & 16383;
  const float* X = (which==1)? ls : lc;
  const float* W = (which==0)? Wl : (which==1? Ws : Wc);
  const float* bias = (which==0)? bl : (which==1? bs : bc);
  float scale = expf( (which==0)? *scl : (which==1? *scs : *scc) );
  const float* Yr = Y + (size_t)which*BND*NDP + (size_t)row*NDP;
  int t = threadIdx.x; // 128
  // y128 = dot(X[row], W[128]) + b[128]
  float xa = X[(size_t)row*NDP + t];
  float part = xa * W[128*NDP + t];
  if (t==0) part += X[(size_t)row*NDP + 128] * W[128*NDP + 128];
  float v = part;
  #pragma unroll
  for (int o=32;o>0;o>>=1) v += __shfl_down(v,o,64);
  if ((t&63)==0) red[t>>6]=v;
  __syncthreads();
  float y128 = red[0]+red[1] + bias[128];
  __syncthreads();
  float yj = Yr[t]; // j = t, 0..127
  if (t==0) sh_y0 = yj;
  float sv = (t>=1)? yj*yj : y128*y128;
  v = sv;
  #pragma unroll
  for (int o=32;o>0;o>>=1) v += __shfl_down(v,o,64);
  if ((t&63)==0) red[t>>6]=v;
  __syncthreads();
  float s2 = fmaxf(red[0]+red[1], 1e-8f);
  float y0 = sh_y0;
  float time = scale/(1.0f+expf(-y0)) + 1.1f;
  float fac = sqrtf((time*time - 1.0f)/s2);
  if (which==0){
    float* out = Lw + (size_t)row*NDP;
    if (t==0){ out[0] = time; out[128] = y128*fac; }
    else out[t] = yj*fac;
  } else {
    float* out = ((which==1)? Ps : Pc) + (size_t)row*NK;
    float inv = fac/(time + SQRTK);
    if (t==0) out[127] = y128*inv;
    else out[t-1] = yj*inv;
  }
}

// ---------------- K3: L = lorentz_tanh(ls @ Lw^T); also Ln and L[:,:,0] ----------------
__global__ void k_gemm1(const float* __restrict__ lsv, const float* __restrict__ Lwv,
                        float* __restrict__ L, float* __restrict__ Ln){
  __shared__ __align__(16) float As_[64][68];
  __shared__ __align__(16) float Bs_[64][68];
  __shared__ float redT[64][17];
  int b = blockIdx.x >> 4;
  int s0 = (blockIdx.x & 15) * 64;
  int t = threadIdx.x;
  int tr = t>>4, tc = t&15;
  const float* lsb = lsv + ((size_t)b*NN + s0)*NDP;
  const float* Lwb = Lwv + (size_t)b*NN*NDP;
  float Treg[4] = {0,0,0,0};
  for (int ct=0; ct<16; ++ct){
    float acc[4][4] = {};
    for (int half=0; half<2; ++half){
      int d0 = half*68;
      __syncthreads();
      for (int i=t;i<64*68;i+=256){ int r=i/68,d=i%68;
        As_[r][d] = (d0+d<NDP) ? lsb[(size_t)r*NDP + d0+d] : 0.f; }
      for (int i=t;i<64*68;i+=256){ int r=i/68,d=i%68;
        Bs_[r][d] = (d0+d<NDP) ? Lwb[(size_t)(ct*64+r)*NDP + d0+d] : 0.f; }
      __syncthreads();
      for (int kk=0;kk<68;kk+=4){
        float4 a[4],b4[4];
        #pragma unroll
        for (int i=0;i<4;i++) a[i] = *(const float4*)&As_[tr*4+i][kk];
        #pragma unroll
        for (int q=0;q<4;q++) b4[q] = *(const float4*)&Bs_[tc+16*q][kk];
        #pragma unroll
        for (int i=0;i<4;i++)
          #pragma unroll
          for (int q=0;q<4;q++)
            acc[i][q] += a[i].x*b4[q].x + a[i].y*b4[q].y + a[i].z*b4[q].z + a[i].w*b4[q].w;
      }
    }
    #pragma unroll
    for (int i=0;i<4;i++){
      int sr = s0 + tr*4 + i;
      #pragma unroll
      for (int q=0;q<4;q++){
        int cc = ct*64 + tc + 16*q;
        if (cc > 0){
          float vv = tanhf(acc[i][q]);
          L[((size_t)b*NN + sr)*NN + cc] = vv;
          Treg[i] += vv*vv;
        }
      }
    }
  }
  #pragma unroll
  for (int i=0;i<4;i++) redT[tr*4+i][tc] = Treg[i];
  __syncthreads();
  if (t < 64){
    float T = 0;
    #pragma unroll
    for (int g=0; g<16; ++g) T += redT[t][g];
    int sr = s0 + t;
    L[((size_t)b*NN + sr)*NN + 0] = sqrtf(1.0f + T);
    Ln[(size_t)b*NN + sr] = sqrtf(1.0f + 2.0f*T);
  }
}

// ---------------- K4: mxs = L @ Pc ----------------
__global__ void k_gemm2(const float* __restrict__ L, const float* __restrict__ Pcv,
                        float* __restrict__ mxs){
  __shared__ __align__(16) float As_[64][68];
  __shared__ __align__(16) float Bs_[64][68];
  int b = blockIdx.x >> 4;
  int s0 = (blockIdx.x & 15)*64;
  int k0 = blockIdx.y * 64;
  int t = threadIdx.x;
  int tr = t>>4, tc = t&15;
  float acc[4][4] = {};
  for (int ch=0; ch<16; ++ch){
    __syncthreads();
    for (int i=t;i<64*64;i+=256){ int r=i>>6, cc=i&63;
      As_[r][cc] = L[((size_t)b*NN + s0+r)*NN + ch*64+cc]; }
    for (int i=t;i<64*64;i+=256){ int kk=i&63, cc=i>>6;
      Bs_[kk][cc] = Pcv[((size_t)b*NN + ch*64+cc)*NK + k0+kk]; }
    __syncthreads();
    for (int kk=0;kk<64;kk+=4){
      float4 a[4],b4[4];
      #pragma unroll
      for (int i=0;i<4;i++) a[i] = *(const float4*)&As_[tr*4+i][kk];
      #pragma unroll
      for (int q=0;q<4;q++) b4[q] = *(const float4*)&Bs_[tc+16*q][kk];
      #pragma unroll
      for (int i=0;i<4;i++)
        #pragma unroll
        for (int q=0;q<4;q++)
          acc[i][q] += a[i].x*b4[q].x + a[i].y*b4[q].y + a[i].z*b4[q].z + a[i].w*b4[q].w;
    }
  }
  #pragma unroll
  for (int i=0;i<4;i++)
    #pragma unroll
    for (int q=0;q<4;q++)
      mxs[((size_t)b*NN + s0+tr*4+i)*NK + k0+tc+16*q] = acc[i][q];
}

// ---------------- K5: mxc = L^T @ Ps; also LTn ----------------
__global__ void k_gemm3(const float* __restrict__ L, const float* __restrict__ Psv,
                        float* __restrict__ mxc, float* __restrict__ LTn){
  __shared__ __align__(16) float As_[64][68];
  __shared__ __align__(16) float Bs_[64][68];
  __shared__ float red[256];
  int b = blockIdx.x >> 4;
  int c0 = (blockIdx.x & 15)*64;
  int k0 = blockIdx.y * 64;
  int t = threadIdx.x;
  int tr = t>>4, tc = t&15;
  float acc[4][4] = {};
  float sq = 0.f;
  for (int ch=0; ch<16; ++ch){
    __syncthreads();
    for (int i=t;i<64*64;i+=256){
      int ci = i&63, ss = i>>6;
      float v = L[((size_t)b*NN + ch*64+ss)*NN + c0+ci];
      As_[ci][ss] = v;
      sq += v*v;
    }
    for (int i=t;i<64*64;i+=256){ int kk=i&63, ss=i>>6;
      Bs_[kk][ss] = Psv[((size_t)b*NN + ch*64+ss)*NK + k0+kk]; }
    __syncthreads();
    for (int kk=0;kk<64;kk+=4){
      float4 a[4],b4[4];
      #pragma unroll
      for (int i=0;i<4;i++) a[i] = *(const float4*)&As_[tr*4+i][kk];
      #pragma unroll
      for (int q=0;q<4;q++) b4[q] = *(const float4*)&Bs_[tc+16*q][kk];
      #pragma unroll
      for (int i=0;i<4;i++)
        #pragma unroll
        for (int q=0;q<4;q++)
          acc[i][q] += a[i].x*b4[q].x + a[i].y*b4[q].y + a[i].z*b4[q].z + a[i].w*b4[q].w;
    }
  }
  #pragma unroll
  for (int i=0;i<4;i++)
    #pragma unroll
    for (int q=0;q<4;q++)
      mxc[((size_t)b*NN + c0+tr*4+i)*NK + k0+tc+16*q] = acc[i][q];
  if (blockIdx.y == 0){
    red[t] = sq;
    __syncthreads();
    if (t < 64){
      float tot = red[t]+red[t+64]+red[t+128]+red[t+192];
      LTn[(size_t)b*NN + c0 + t] = fmaxf(sqrtf(tot), 1e-15f);
    }
  }
}

// ---------------- K6: fused Mobius/Lorentz epilogue -> logits ----------------
__global__ void k_epilogue(const float* __restrict__ mxs, const float* __restrict__ mxc,
    const float* __restrict__ Ps, const float* __restrict__ Pc,
    const float* __restrict__ Ln, const float* __restrict__ LTn,
    const float* __restrict__ whs, const float* __restrict__ whc,
    float* __restrict__ logit){
  __shared__ float red[2];
  int blk = blockIdx.x;
  int side = blk >> 14;
  int row = blk & 16383;
  const float* mx = (side? mxc : mxs) + (size_t)row*NK;
  const float* x  = (side? Pc : Ps) + (size_t)row*NK;
  float xn = (side? LTn : Ln)[row];
  const float* wh = side? whc : whs;
  int t = threadIdx.x; // 128
  float mxj = mx[t];
  float xj = x[t];
  float mx2 = bsum128(mxj*mxj, red);
  float mxn = fmaxf(sqrtf(mx2), 1e-15f);
  float at1 = artanh_clip(xn);
  float fac = tanhf(mxn/xn*at1)/mxn;
  float yj = fac*mxj;
  float xy = bsum128(xj*yj, red);
  float x2 = bsum128(xj*xj, red);
  float y2 = bsum128(yj*yj, red);
  float den = fmaxf(1.0f + 2.0f*xy + x2*y2, 1e-15f);
  float ma = ((1.0f+2.0f*xy+y2)*xj + (1.0f-x2)*yj)/den;
  float m2 = bsum128(ma*ma, red);
  float sp = SQRTK*2.0f*ma/(1.0f - m2 + 1e-6f);
  float h = tanhf(sp);
  float S = bsum128(h*h, red);
  float timev = sqrtf(1.0f + S);
  float hn = fmaxf(sqrtf(1.0f + 2.0f*S), 1e-15f);
  float dotv = bsum128(h*wh[1+t], red) + timev*wh[0];
  float at2 = artanh_clip(hn);
  float mn = fmaxf(fabsf(dotv), 1e-15f);
  float lg = tanhf(mn/hn*at2)*(dotv/mn);
  if (t==0) logit[(size_t)side*BND + row] = lg;
}

// ---------------- K7: softmax over n per (side,b) ----------------
__global__ void k_softmax(const float* __restrict__ logit,
                          float* __restrict__ outAs, float* __restrict__ outAc){
  __shared__ float red[4];
  int side = blockIdx.x >> 4;
  int b = blockIdx.x & 15;
  const float* lg = logit + (size_t)side*BND + (size_t)b*NN;
  float* out = (side? outAc : outAs) + (size_t)b*NN;
  int t = threadIdx.x; // 256
  float l[4]; float m = -1e30f;
  #pragma unroll
  for (int i=0;i<4;i++){ l[i] = lg[t+256*i]; m = fmaxf(m,l[i]); }
  #pragma unroll
  for (int o=32;o>0;o>>=1) m = fmaxf(m, __shfl_down(m,o,64));
  if ((t&63)==0) red[t>>6]=m;
  __syncthreads();
  m = fmaxf(fmaxf(red[0],red[1]), fmaxf(red[2],red[3]));
  __syncthreads();
  float s = 0.f; float e[4];
  #pragma unroll
  for (int i=0;i<4;i++){ e[i] = expf(l[i]-m); s += e[i]; }
  #pragma unroll
  for (int o=32;o>0;o>>=1) s += __shfl_down(s,o,64);
  if ((t&63)==0) red[t>>6]=s;
  __syncthreads();
  s = red[0]+red[1]+red[2]+red[3];
  float invs = 1.0f/s;
  #pragma unroll
  for (int i=0;i<4;i++) out[t+256*i] = e[i]*invs;
}

// ---------------- K8: lorentz centroid ----------------
__global__ void k_centroid(const float* __restrict__ As0, const float* __restrict__ Ac0,
    const float* __restrict__ ls, const float* __restrict__ lc, float* __restrict__ co){
  __shared__ float Psh[NN];
  __shared__ float avgS[NDP];
  __shared__ float red[4];
  int side = blockIdx.x>>4, b = blockIdx.x&15;
  const float* P = (side? Ac0 : As0) + (size_t)b*NN;
  const float* l = (side? lc : ls) + (size_t)b*NN*NDP;
  int t = threadIdx.x; // 256
  for (int i=t;i<NN;i+=256) Psh[i] = P[i];
  __syncthreads();
  float acc = 0.f;
  if (t < NDP){
    for (int n=0;n<NN;++n) acc += Psh[n]*l[(size_t)n*NDP + t];
    avgS[t] = acc;
  }
  __syncthreads();
  float val = (t>=1 && t<NDP)? acc*acc : 0.f;
  #pragma unroll
  for (int o=32;o>0;o>>=1) val += __shfl_down(val,o,64);
  if ((t&63)==0) red[t>>6]=val;
  __syncthreads();
  float s1 = red[0]+red[1]+red[2]+red[3];
  float inner = s1 - avgS[0]*avgS[0];
  float dn = sqrtf(fmaxf(fabsf(inner), 1e-8f));
  if (t < NDP) co[((size_t)side*NB + b)*NDP + t] = acc/dn;
}

// ---------------- K9: assemble co_sc ----------------
__global__ void k_final(const float* __restrict__ co, float* __restrict__ out){
  __shared__ float red[4];
  int b = blockIdx.x, t = threadIdx.x; // 256
  float sp = (t<128)? co[((size_t)b)*NDP + 1 + t]
                    : co[((size_t)(NB + b))*NDP + 1 + (t-128)];
  float v = sp*sp;
  #pragma unroll
  for (int o=32;o>0;o>>=1) v += __shfl_down(v,o,64);
  if ((t&63)==0) red[t>>6]=v;
  __syncthreads();
  float S = red[0]+red[1]+red[2]+red[3];
  float* ob = out + (size_t)b*257;
  if (t==0) ob[0] = sqrtf(1.0f + S);
  ob[1+t] = sp;
}

extern "C" void kernel_launch(void* const* d_in, const int* in_sizes, int n_in,
                              void* d_out, int out_size, void* d_ws, size_t ws_size,
                              hipStream_t stream) {
  const float* srep = (const float*)d_in[0];
  const float* crep = (const float*)d_in[1];
  const float* Wl_w = (const float*)d_in[2];
  const float* Wl_b = (const float*)d_in[3];
  const float* Wl_s = (const float*)d_in[4];
  const float* Ws_w = (const float*)d_in[5];
  const float* Ws_b = (const float*)d_in[6];
  const float* Ws_s = (const float*)d_in[7];
  const float* Wc_w = (const float*)d_in[8];
  const float* Wc_b = (const float*)d_in[9];
  const float* Wc_s = (const float*)d_in[10];
  const float* whs  = (const float*)d_in[11];
  const float* whc  = (const float*)d_in[12];
  float* out = (float*)d_out;

  float* ws = (float*)d_ws;
  size_t off = 0;
  float* ls  = ws + off; off += (size_t)BND*NDP;     // 2113536
  float* lc  = ws + off; off += (size_t)BND*NDP;
  float* Lw  = ws + off; off += (size_t)BND*NDP;
  float* Ps  = ws + off; off += (size_t)BND*NK;
  float* Pc  = ws + off; off += (size_t)BND*NK;
  float* L   = ws + off; off += (size_t)BND*NN;      // 67 MB
  float* mxs = ws + off; off += (size_t)BND*NK;
  float* mxc = ws + off; off += (size_t)BND*NK;
  float* Ln  = ws + off; off += (size_t)BND;
  float* LTn = ws + off; off += (size_t)BND;
  float* logit = ws + off; off += (size_t)2*BND;
  float* co  = ws + off; off += (size_t)2*NB*NDP;
  float* Y   = L;  // alias: Y dead before L is written

  float* outAs = out + NB*257;
  float* outAc = out + NB*257 + NB*NN;

  k_p2l<<<2*BND, 128, 0, stream>>>(srep, crep, ls, lc);
  k_lin_gemm<<<dim3(BND/64, 2, 3), 256, 0, stream>>>(ls, lc, Wl_w, Ws_w, Wc_w, Wl_b, Ws_b, Wc_b, Y);
  k_lin_post<<<3*BND, 128, 0, stream>>>(ls, lc, Wl_w, Ws_w, Wc_w, Wl_b, Ws_b, Wc_b,
                                        Wl_s, Ws_s, Wc_s, Y, Lw, Ps, Pc);
  k_gemm1<<<NB*16, 256, 0, stream>>>(ls, Lw, L, Ln);
  k_gemm2<<<dim3(NB*16, 2), 256, 0, stream>>>(L, Pc, mxs);
  k_gemm3<<<dim3(NB*16, 2), 256, 0, stream>>>(L, Ps, mxc, LTn);
  k_epilogue<<<2*BND, 128, 0, stream>>>(mxs, mxc, Ps, Pc, Ln, LTn, whs, whc, logit);
  k_softmax<<<32, 256, 0, stream>>>(logit, outAs, outAc);
  k_centroid<<<32, 256, 0, stream>>>(outAs, outAc, ls, lc, co);
  k_final<<<NB, 256, 0, stream>>>(co, out);
}

// Round 2
// 168.432 us; speedup vs baseline: 4.5929x; 4.5929x over previous
//
#include <hip/hip_runtime.h>

#define NN 1024
#define NB 16
#define SQRTK 11.313708498984761f

typedef float f32x4 __attribute__((ext_vector_type(4)));
typedef short bf16x8 __attribute__((ext_vector_type(8)));
typedef unsigned short ushort_t;
typedef unsigned int uint_t;

__device__ __forceinline__ ushort_t f2bf(float f){
  uint_t u = __float_as_uint(f);
  u += 0x7fffu + ((u>>16)&1u);
  return (ushort_t)(u>>16);
}
__device__ __forceinline__ float bf2f(ushort_t h){ return __uint_as_float(((uint_t)h)<<16); }

__device__ __forceinline__ float fast_tanh(float x){
  x = fminf(fmaxf(x,-15.f),15.f);
  float e = __expf(2.f*x);
  return (e-1.f)/(e+1.f);
}

__device__ __forceinline__ float artanh_clip(float x){
  x = fminf(fmaxf(x, -1.0f+1e-5f), 1.0f-1e-5f);
  return 0.5f*logf((1.0f+x)/(1.0f-x));
}

// Stage nrows rows of 256B (128 bf16) each from row-strided global into LDS.
// LDS layout: byte(r, slot) = r*256 + (slot ^ (r&7))*16  (slot = 16B unit).
// Source is pre-swizzled with the same involution so linear global_load_lds
// dest + swizzled ds_read agree (guide rule #21).
__device__ __forceinline__ void stage_swz(const ushort_t* __restrict__ g, int row_stride,
                                          char* ldsbase, int nrows, int tid){
  int lane = tid & 63;
  int w = tid >> 6;
  int ninst = nrows >> 2;
  int r_in = lane >> 4;
  int s_in = lane & 15;
  for (int inst = w; inst < ninst; inst += 4){
    int r = (inst<<2) + r_in;
    int s = s_in ^ (r & 7);
    const ushort_t* src = g + (size_t)r*row_stride + (s<<3);
    int instU = __builtin_amdgcn_readfirstlane(inst);
    __builtin_amdgcn_global_load_lds((const __attribute__((address_space(1))) void*)src,
        (__attribute__((address_space(3))) void*)(ldsbase + (instU<<10)), 16, 0, 0);
  }
}

__device__ __forceinline__ bf16x8 ldsfrag(const char* base, int r, int slot){
  return *(const bf16x8*)(base + ((r<<8) + ((slot ^ (r&7))<<4)));
}

// ---------------- K1: p2l -> bf16 space + fp32 time ----------------
__global__ void k_p2l(const float* __restrict__ S, const float* __restrict__ C,
                      ushort_t* __restrict__ lsb, ushort_t* __restrict__ lcb,
                      float* __restrict__ lst, float* __restrict__ lct){
  int gr = (blockIdx.x<<2) + (threadIdx.x>>6);
  int lane = threadIdx.x & 63;
  const float* in; ushort_t* ob; float* ot;
  if (gr < (NB<<10)){ in = S + (size_t)gr*128; ob = lsb + (size_t)gr*128; ot = lst+gr; }
  else { int r = gr - (NB<<10); in = C + (size_t)r*128; ob = lcb + (size_t)r*128; ot = lct+r; }
  float2 v = ((const float2*)in)[lane];
  float sq = v.x*v.x + v.y*v.y;
  #pragma unroll
  for (int o=32;o>0;o>>=1) sq += __shfl_xor(sq, o, 64);
  float inv = SQRTK/(1.f - sq + 1e-6f);
  uint_t pack = (uint_t)f2bf(2.f*v.x*inv) | ((uint_t)f2bf(2.f*v.y*inv)<<16);
  ((uint_t*)ob)[lane] = pack;
  if (lane==0) *ot = (1.f+sq)*inv;
}

// ---------------- K2: weight prep (bf16 space part + fp32 time col) ----------------
__global__ void k_prepW(const float* __restrict__ Wl, const float* __restrict__ Ws,
                        const float* __restrict__ Wc, ushort_t* __restrict__ Wb,
                        float* __restrict__ Wt){
  int j = blockIdx.x, w = blockIdx.y, t = threadIdx.x; // 128 threads
  const float* W = (w==0)? Wl : (w==1? Ws : Wc);
  Wb[((size_t)w<<14) + (j<<7) + t] = f2bf(W[j*129 + 1 + t]);
  if (t==0) Wt[(w<<7)+j] = W[j*129];
}

// ---------------- K3: Y = X@W.T (cols 0..127) via MFMA + rank-1 ----------------
__global__ __launch_bounds__(256) void k_lin(const ushort_t* __restrict__ lsb,
    const ushort_t* __restrict__ lcb, const float* __restrict__ lst, const float* __restrict__ lct,
    const ushort_t* __restrict__ Wb, const float* __restrict__ Wt,
    const float* __restrict__ bl, const float* __restrict__ bs, const float* __restrict__ bc,
    float* __restrict__ Y){
  __shared__ __attribute__((aligned(1024))) char sm[48*1024];
  int which = blockIdx.y;
  int m0 = blockIdx.x << 6;
  const ushort_t* A = ((which==1)? lsb : lcb) + (size_t)m0*128;
  const float* At = ((which==1)? lst : lct) + m0;
  const ushort_t* B = Wb + ((size_t)which<<14);
  const float* bias = (which==0)? bl : (which==1? bs : bc);
  float* Yw = Y + (((size_t)which<<14) + m0)*128;
  int tid = threadIdx.x, lane = tid&63;
  int w = tid>>6, wr = w>>1, wc = w&1, lo = lane&15, hi = lane>>4;
  f32x4 acc[2][4];
  #pragma unroll
  for (int i=0;i<2;i++)
    #pragma unroll
    for (int q=0;q<4;q++) acc[i][q] = (f32x4){0.f,0.f,0.f,0.f};
  char* Al = sm; char* Bl = sm + 16*1024;
  stage_swz(A, 128, Al, 64, tid);
  stage_swz(B, 128, Bl, 128, tid);
  __syncthreads();
  #pragma unroll
  for (int kc=0; kc<4; ++kc){
    bf16x8 av[2], bv[4];
    #pragma unroll
    for (int i=0;i<2;i++) av[i] = ldsfrag(Al, (wr<<5)+(i<<4)+lo, (kc<<2)+hi);
    #pragma unroll
    for (int q=0;q<4;q++) bv[q] = ldsfrag(Bl, (wc<<6)+(q<<4)+lo, (kc<<2)+hi);
    #pragma unroll
    for (int i=0;i<2;i++)
      #pragma unroll
      for (int q=0;q<4;q++)
        acc[i][q] = __builtin_amdgcn_mfma_f32_16x16x32_bf16(av[i], bv[q], acc[i][q], 0,0,0);
  }
  #pragma unroll
  for (int i=0;i<2;i++)
    #pragma unroll
    for (int q=0;q<4;q++)
      #pragma unroll
      for (int j=0;j<4;j++){
        int rl = (wr<<5)+(i<<4)+(hi<<2)+j;
        int cl = (wc<<6)+(q<<4)+lo;
        Yw[(size_t)rl*128 + cl] = acc[i][q][j] + At[rl]*Wt[(which<<7)+cl] + bias[cl];
      }
}

// ---------------- K4: lorentz_linear nonlinearity ----------------
__global__ void k_post(const ushort_t* __restrict__ lsb, const ushort_t* __restrict__ lcb,
    const float* __restrict__ lst, const float* __restrict__ lct,
    const float* __restrict__ Wl, const float* __restrict__ Ws, const float* __restrict__ Wc,
    const float* __restrict__ bl, const float* __restrict__ bs, const float* __restrict__ bc,
    const float* __restrict__ scl, const float* __restrict__ scs, const float* __restrict__ scc,
    const float* __restrict__ Y, ushort_t* __restrict__ Lwb, float* __restrict__ Lwt,
    ushort_t* __restrict__ Psb, ushort_t* __restrict__ Pcb){
  __shared__ float red[2];
  __shared__ float sh_y0;
  int blk = blockIdx.x;
  int which = blk >> 14, row = blk & 16383;
  const ushort_t* Xb = (which==1)? lsb : lcb;
  const float* Xt = (which==1)? lst : lct;
  const float* W = (which==0)? Wl : (which==1? Ws : Wc);
  const float* bias = (which==0)? bl : (which==1? bs : bc);
  float scale = __expf((which==0)? *scl : (which==1? *scs : *scc));
  const float* Yr = Y + (((size_t)which<<14) + row)*128;
  int t = threadIdx.x; // 128
  float part = bf2f(Xb[(size_t)row*128 + t]) * W[128*129 + 1 + t];
  if (t==0) part += Xt[row]*W[128*129];
  float v = part;
  #pragma unroll
  for (int o=32;o>0;o>>=1) v += __shfl_down(v,o,64);
  if ((t&63)==0) red[t>>6]=v;
  __syncthreads();
  float y128 = red[0]+red[1] + bias[128];
  float yj = Yr[t];
  if (t==0) sh_y0 = yj;
  __syncthreads();
  float sv = (t>=1)? yj*yj : y128*y128;
  v = sv;
  #pragma unroll
  for (int o=32;o>0;o>>=1) v += __shfl_down(v,o,64);
  if ((t&63)==0) red[t>>6]=v;
  __syncthreads();
  float s2 = fmaxf(red[0]+red[1], 1e-8f);
  float y0 = sh_y0;
  float time = scale/(1.f+__expf(-y0)) + 1.1f;
  float fac = sqrtf((time*time-1.f)/s2);
  if (which==0){
    if (t==0){ Lwt[row]=time; Lwb[(size_t)row*128+127] = f2bf(y128*fac); }
    else Lwb[(size_t)row*128 + t-1] = f2bf(yj*fac);
  } else {
    ushort_t* out = ((which==1)? Psb : Pcb) + (size_t)row*128;
    float iv = fac/(time + SQRTK);
    if (t==0) out[127] = f2bf(y128*iv);
    else out[t-1] = f2bf(yj*iv);
  }
}

// ---------------- K5: transpose Ps/Pc -> PsT/PcT (bf16, [k][n]) ----------------
__global__ void k_trP(const ushort_t* __restrict__ Psb, const ushort_t* __restrict__ Pcb,
                      ushort_t* __restrict__ PsT, ushort_t* __restrict__ PcT){
  __shared__ ushort_t sm[128][136];
  int nt = blockIdx.x, b = blockIdx.y, which = blockIdx.z;
  const ushort_t* src = (which? Pcb : Psb) + (((size_t)(b<<10)) + (nt<<7))*128;
  ushort_t* dst = (which? PcT : PsT) + ((size_t)b<<17) + (nt<<7);
  int tid = threadIdx.x;
  for (int idx = tid; idx < 2048; idx += 256){
    int n = idx >> 4, sl = idx & 15;
    bf16x8 v = *(const bf16x8*)(src + (size_t)n*128 + (sl<<3));
    #pragma unroll
    for (int e=0;e<8;e++) sm[(sl<<3)+e][n] = (ushort_t)v[e];
  }
  __syncthreads();
  for (int idx = tid; idx < 2048; idx += 256){
    int k = idx >> 4, sl = idx & 15;
    bf16x8 v = *(const bf16x8*)(&sm[k][sl<<3]);
    *(bf16x8*)(dst + (size_t)k*NN + (sl<<3)) = v;
  }
}

// ---------------- K6: L = tanh(ls.Lw^T) bf16, + L^T, + row-sum partials ----------------
__global__ __launch_bounds__(256) void k_g1(const ushort_t* __restrict__ lsb,
    const float* __restrict__ lst, const ushort_t* __restrict__ Lwb, const float* __restrict__ Lwt,
    ushort_t* __restrict__ L, ushort_t* __restrict__ LT, float* __restrict__ Tpart){
  __shared__ __attribute__((aligned(1024))) char sm[48*1024];
  __shared__ float red[64][33];
  int bid = blockIdx.x;
  int ct = bid & 7, st = (bid>>3)&15, b = bid>>7;
  int s0 = st<<6, c0 = ct<<7;
  const ushort_t* A = lsb + ((size_t)(b<<10)+s0)*128;
  const ushort_t* Bm = Lwb + ((size_t)(b<<10)+c0)*128;
  int tid=threadIdx.x, lane=tid&63;
  int w=tid>>6, wr=w>>1, wc=w&1, lo=lane&15, hi=lane>>4;
  f32x4 acc[2][4];
  #pragma unroll
  for (int i=0;i<2;i++)
    #pragma unroll
    for (int q=0;q<4;q++) acc[i][q] = (f32x4){0.f,0.f,0.f,0.f};
  char* Al = sm; char* Bl = sm + 16*1024;
  stage_swz(A, 128, Al, 64, tid);
  stage_swz(Bm, 128, Bl, 128, tid);
  __syncthreads();
  #pragma unroll
  for (int kc=0; kc<4; ++kc){
    bf16x8 av[2], bv[4];
    #pragma unroll
    for (int i=0;i<2;i++) av[i] = ldsfrag(Al, (wr<<5)+(i<<4)+lo, (kc<<2)+hi);
    #pragma unroll
    for (int q=0;q<4;q++) bv[q] = ldsfrag(Bl, (wc<<6)+(q<<4)+lo, (kc<<2)+hi);
    #pragma unroll
    for (int i=0;i<2;i++)
      #pragma unroll
      for (int q=0;q<4;q++)
        acc[i][q] = __builtin_amdgcn_mfma_f32_16x16x32_bf16(av[i], bv[q], acc[i][q], 0,0,0);
  }
  float lwt4[4], lts[2][4];
  #pragma unroll
  for (int q=0;q<4;q++) lwt4[q] = Lwt[(b<<10)+c0+(wc<<6)+(q<<4)+lo];
  #pragma unroll
  for (int i=0;i<2;i++)
    #pragma unroll
    for (int j=0;j<4;j++) lts[i][j] = lst[(b<<10)+s0+(wr<<5)+(i<<4)+(hi<<2)+j];
  float p[2][4] = {};
  #pragma unroll
  for (int i=0;i<2;i++)
    #pragma unroll
    for (int q=0;q<4;q++)
      #pragma unroll
      for (int j=0;j<4;j++){
        float d = acc[i][q][j] + lts[i][j]*lwt4[q];
        float vv = fast_tanh(d);
        int rl = (wr<<5)+(i<<4)+(hi<<2)+j;
        int cl = (wc<<6)+(q<<4)+lo;
        size_t gs = (size_t)(b<<10)+s0+rl;
        size_t gc = (size_t)(b<<10)+c0+cl;
        L[gs*NN + c0+cl] = f2bf(vv);
        LT[gc*NN + s0+rl] = f2bf(vv);
        if (c0+cl != 0) p[i][j] += vv*vv;
      }
  #pragma unroll
  for (int i=0;i<2;i++)
    #pragma unroll
    for (int j=0;j<4;j++) red[(wr<<5)+(i<<4)+(hi<<2)+j][lo+(wc<<4)] = p[i][j];
  __syncthreads();
  if (tid < 64){
    float T=0.f;
    #pragma unroll
    for (int cc=0;cc<32;cc++) T += red[tid][cc];
    Tpart[((size_t)ct<<14) + (b<<10)+s0+tid] = T;
  }
}

// ---------------- K7: fix L[:, :, 0], LT[:, 0, :], Ln ----------------
__global__ void k_Lfix(const float* __restrict__ Tpart, ushort_t* __restrict__ L,
                       ushort_t* __restrict__ LT, float* __restrict__ Ln){
  int sg = blockIdx.x*256 + threadIdx.x; // 0..16383
  float T = 0.f;
  #pragma unroll
  for (int ct=0; ct<8; ++ct) T += Tpart[((size_t)ct<<14) + sg];
  float timev = sqrtf(1.f + T);
  int b = sg >> 10, s = sg & 1023;
  L[(size_t)sg*NN] = f2bf(timev);
  LT[((size_t)(b<<10))*NN + s] = f2bf(timev);
  Ln[sg] = sqrtf(1.f + 2.f*T);
}

// ---------------- K8: LTn (column norms of L = row norms of LT) ----------------
__global__ void k_LTn(const ushort_t* __restrict__ LT, float* __restrict__ LTn){
  int cg = (blockIdx.x<<2) + (threadIdx.x>>6);
  int lane = threadIdx.x & 63;
  const ushort_t* row = LT + (size_t)cg*NN + (lane<<4);
  float s = 0.f;
  #pragma unroll
  for (int h=0; h<2; ++h){
    bf16x8 vv = *(const bf16x8*)(row + (h<<3));
    #pragma unroll
    for (int e=0;e<8;e++){ float f = bf2f((ushort_t)vv[e]); s += f*f; }
  }
  #pragma unroll
  for (int o=32;o>0;o>>=1) s += __shfl_xor(s, o, 64);
  if (lane==0) LTn[cg] = fmaxf(sqrtf(s), 1e-15f);
}

// ---------------- K9: mxs = L@PcT^T ; mxc = LT@PsT^T ----------------
__global__ __launch_bounds__(256) void k_mx(const ushort_t* __restrict__ L,
    const ushort_t* __restrict__ LT, const ushort_t* __restrict__ PcT,
    const ushort_t* __restrict__ PsT, float* __restrict__ mxs, float* __restrict__ mxc){
  __shared__ __attribute__((aligned(1024))) char sm[48*1024];
  int side = blockIdx.y;
  int b = blockIdx.x >> 4;
  int m0 = (blockIdx.x & 15) << 6;
  const ushort_t* A = (side? LT : L) + ((size_t)(b<<10) + m0)*NN;
  const ushort_t* B = (side? PsT : PcT) + ((size_t)b<<17);
  float* C = (side? mxc : mxs) + ((size_t)(b<<10) + m0)*128;
  int tid = threadIdx.x, lane = tid&63;
  int w = tid>>6, wr = w>>1, wc = w&1, lo = lane&15, hi = lane>>4;
  f32x4 acc[2][4];
  #pragma unroll
  for (int i=0;i<2;i++)
    #pragma unroll
    for (int q=0;q<4;q++) acc[i][q] = (f32x4){0.f,0.f,0.f,0.f};
  char* Al = sm; char* Bl = sm + 16*1024;
  for (int ch=0; ch<8; ++ch){
    __syncthreads();
    stage_swz(A + (ch<<7), NN, Al, 64, tid);
    stage_swz(B + (ch<<7), NN, Bl, 128, tid);
    __syncthreads();
    #pragma unroll
    for (int kc=0; kc<4; ++kc){
      bf16x8 av[2], bv[4];
      #pragma unroll
      for (int i=0;i<2;i++) av[i] = ldsfrag(Al, (wr<<5)+(i<<4)+lo, (kc<<2)+hi);
      #pragma unroll
      for (int q=0;q<4;q++) bv[q] = ldsfrag(Bl, (wc<<6)+(q<<4)+lo, (kc<<2)+hi);
      #pragma unroll
      for (int i=0;i<2;i++)
        #pragma unroll
        for (int q=0;q<4;q++)
          acc[i][q] = __builtin_amdgcn_mfma_f32_16x16x32_bf16(av[i], bv[q], acc[i][q], 0,0,0);
    }
  }
  #pragma unroll
  for (int i=0;i<2;i++)
    #pragma unroll
    for (int q=0;q<4;q++)
      #pragma unroll
      for (int j=0;j<4;j++){
        int rl = (wr<<5)+(i<<4)+(hi<<2)+j;
        int cl = (wc<<6)+(q<<4)+lo;
        C[(size_t)rl*128 + cl] = acc[i][q][j];
      }
}

// ---------------- K10: fused Mobius/Lorentz epilogue -> logits ----------------
__device__ __forceinline__ float bsum128(float v, volatile float* red){
  #pragma unroll
  for (int o=32;o>0;o>>=1) v += __shfl_down(v,o,64);
  int t = threadIdx.x;
  __syncthreads();
  if ((t&63)==0) red[t>>6] = v;
  __syncthreads();
  return red[0]+red[1];
}

__global__ void k_epi(const float* __restrict__ mxs, const float* __restrict__ mxc,
    const ushort_t* __restrict__ Psb, const ushort_t* __restrict__ Pcb,
    const float* __restrict__ Ln, const float* __restrict__ LTn,
    const float* __restrict__ whs, const float* __restrict__ whc, float* __restrict__ logit){
  __shared__ float red[2];
  int blk = blockIdx.x;
  int side = blk >> 14, row = blk & 16383;
  const float* mx = (side? mxc : mxs) + (size_t)row*128;
  const ushort_t* xP = (side? Pcb : Psb) + (size_t)row*128;
  float xn = (side? LTn : Ln)[row];
  const float* wh = side? whc : whs;
  int t = threadIdx.x; // 128
  float mxj = mx[t];
  float xj = bf2f(xP[t]);
  float mx2 = bsum128(mxj*mxj, red);
  float mxn = fmaxf(sqrtf(mx2), 1e-15f);
  float at1 = artanh_clip(xn);
  float fac = tanhf(mxn/xn*at1)/mxn;
  float yj = fac*mxj;
  float xy = bsum128(xj*yj, red);
  float x2 = bsum128(xj*xj, red);
  float y2 = bsum128(yj*yj, red);
  float den = fmaxf(1.0f + 2.0f*xy + x2*y2, 1e-15f);
  float ma = ((1.0f+2.0f*xy+y2)*xj + (1.0f-x2)*yj)/den;
  float m2 = bsum128(ma*ma, red);
  float sp = SQRTK*2.0f*ma/(1.0f - m2 + 1e-6f);
  float h = tanhf(sp);
  float Sh = bsum128(h*h, red);
  float timev = sqrtf(1.0f + Sh);
  float hn = fmaxf(sqrtf(1.0f + 2.0f*Sh), 1e-15f);
  float dotv = bsum128(h*wh[1+t], red) + timev*wh[0];
  float at2 = artanh_clip(hn);
  float mn = fmaxf(fabsf(dotv), 1e-15f);
  float lg = tanhf(mn/hn*at2)*(dotv/mn);
  if (t==0) logit[(side<<14) + row] = lg;
}

// ---------------- K11: softmax ----------------
__global__ void k_softmax(const float* __restrict__ logit,
                          float* __restrict__ outAs, float* __restrict__ outAc){
  __shared__ float red4[4];
  int side = blockIdx.x >> 4;
  int b = blockIdx.x & 15;
  const float* lg = logit + (side<<14) + (b<<10);
  float* out = (side? outAc : outAs) + (b<<10);
  int t = threadIdx.x; // 256
  float l[4]; float m = -1e30f;
  #pragma unroll
  for (int i=0;i<4;i++){ l[i] = lg[t+256*i]; m = fmaxf(m,l[i]); }
  #pragma unroll
  for (int o=32;o>0;o>>=1) m = fmaxf(m, __shfl_down(m,o,64));
  if ((t&63)==0) red4[t>>6]=m;
  __syncthreads();
  m = fmaxf(fmaxf(red4[0],red4[1]), fmaxf(red4[2],red4[3]));
  __syncthreads();
  float s = 0.f; float e[4];
  #pragma unroll
  for (int i=0;i<4;i++){ e[i] = __expf(l[i]-m); s += e[i]; }
  #pragma unroll
  for (int o=32;o>0;o>>=1) s += __shfl_down(s,o,64);
  if ((t&63)==0) red4[t>>6]=s;
  __syncthreads();
  s = red4[0]+red4[1]+red4[2]+red4[3];
  float invs = 1.0f/s;
  #pragma unroll
  for (int i=0;i<4;i++) out[t+256*i] = e[i]*invs;
}

// ---------------- K12: centroid partials ----------------
__global__ void k_cpart(const float* __restrict__ As0, const float* __restrict__ Ac0,
    const ushort_t* __restrict__ lsb, const ushort_t* __restrict__ lcb,
    const float* __restrict__ lst, const float* __restrict__ lct, float* __restrict__ part){
  __shared__ float Psh[128];
  int ch = blockIdx.x, b = blockIdx.y, side = blockIdx.z;
  const float* P = (side? Ac0 : As0) + (b<<10) + (ch<<7);
  const ushort_t* Xb = (side? lcb : lsb) + (((size_t)(b<<10)) + (ch<<7))*128;
  const float* Xt = (side? lct : lst) + (b<<10) + (ch<<7);
  int t = threadIdx.x; // 256
  if (t < 128) Psh[t] = P[t];
  __syncthreads();
  float acc = 0.f;
  if (t < 128){
    for (int n=0; n<128; ++n) acc += Psh[n]*bf2f(Xb[(size_t)n*128 + t]);
  } else if (t == 128){
    for (int n=0; n<128; ++n) acc += Psh[n]*Xt[n];
  }
  if (t <= 128) part[((((size_t)side<<4) + b)*8 + ch)*132 + t] = acc;
}

// ---------------- K13: centroid finalize ----------------
__global__ void k_cfin(const float* __restrict__ part, float* __restrict__ co){
  __shared__ float red4[4];
  __shared__ float t0sh;
  int sb = blockIdx.x; int t = threadIdx.x; // 256
  float a = 0.f;
  if (t <= 128){
    #pragma unroll
    for (int ch=0; ch<8; ++ch) a += part[((size_t)sb*8+ch)*132 + t];
  }
  float val = (t < 128)? a*a : 0.f;
  #pragma unroll
  for (int o=32;o>0;o>>=1) val += __shfl_down(val,o,64);
  if ((t&63)==0) red4[t>>6]=val;
  if (t==128) t0sh = a;
  __syncthreads();
  float S = red4[0]+red4[1]+red4[2]+red4[3];
  float timev = t0sh;
  float inner = S - timev*timev;
  float dn = sqrtf(fmaxf(fabsf(inner), 1e-8f));
  if (t < 128) co[(size_t)sb*132 + 1 + t] = a/dn;
  if (t == 128) co[(size_t)sb*132] = timev/dn;
}

// ---------------- K14: assemble co_sc ----------------
__global__ void k_final(const float* __restrict__ co, float* __restrict__ out){
  __shared__ float red4[4];
  int b = blockIdx.x, t = threadIdx.x; // 256
  float sp = (t<128)? co[(size_t)b*132 + 1 + t]
                    : co[(size_t)(16 + b)*132 + 1 + (t-128)];
  float v = sp*sp;
  #pragma unroll
  for (int o=32;o>0;o>>=1) v += __shfl_down(v,o,64);
  if ((t&63)==0) red4[t>>6]=v;
  __syncthreads();
  float S = red4[0]+red4[1]+red4[2]+red4[3];
  float* ob = out + (size_t)b*257;
  if (t==0) ob[0] = sqrtf(1.0f + S);
  ob[1+t] = sp;
}

extern "C" void kernel_launch(void* const* d_in, const int* in_sizes, int n_in,
                              void* d_out, int out_size, void* d_ws, size_t ws_size,
                              hipStream_t stream) {
  const float* srep = (const float*)d_in[0];
  const float* crep = (const float*)d_in[1];
  const float* Wl_w = (const float*)d_in[2];
  const float* Wl_b = (const float*)d_in[3];
  const float* Wl_s = (const float*)d_in[4];
  const float* Ws_w = (const float*)d_in[5];
  const float* Ws_b = (const float*)d_in[6];
  const float* Ws_s = (const float*)d_in[7];
  const float* Wc_w = (const float*)d_in[8];
  const float* Wc_b = (const float*)d_in[9];
  const float* Wc_s = (const float*)d_in[10];
  const float* whs  = (const float*)d_in[11];
  const float* whc  = (const float*)d_in[12];
  float* out = (float*)d_out;

  char* wsb = (char*)d_ws;
  size_t off = 0;
  auto alloc = [&](size_t n)->char*{ char* p = wsb + off; off += (n + 255) & ~(size_t)255; return p; };
  ushort_t* lsb = (ushort_t*)alloc((size_t)16384*128*2);
  ushort_t* lcb = (ushort_t*)alloc((size_t)16384*128*2);
  float* lst = (float*)alloc(16384*4);
  float* lct = (float*)alloc(16384*4);
  ushort_t* Wb = (ushort_t*)alloc((size_t)3*16384*2);
  float* Wt = (float*)alloc(3*128*4);
  ushort_t* Lwb = (ushort_t*)alloc((size_t)16384*128*2);
  float* Lwt = (float*)alloc(16384*4);
  ushort_t* Psb = (ushort_t*)alloc((size_t)16384*128*2);
  ushort_t* Pcb = (ushort_t*)alloc((size_t)16384*128*2);
  ushort_t* PsT = (ushort_t*)alloc((size_t)16*128*1024*2);
  ushort_t* PcT = (ushort_t*)alloc((size_t)16*128*1024*2);
  ushort_t* L  = (ushort_t*)alloc((size_t)16*1024*1024*2);
  ushort_t* LT = (ushort_t*)alloc((size_t)16*1024*1024*2);
  float* Tpart = (float*)alloc((size_t)8*16384*4);
  float* mxs = (float*)alloc((size_t)16384*128*4);
  float* mxc = (float*)alloc((size_t)16384*128*4);
  float* Ln = (float*)alloc(16384*4);
  float* LTn = (float*)alloc(16384*4);
  float* logit = (float*)alloc((size_t)2*16384*4);
  float* part = (float*)alloc((size_t)2*16*8*132*4);
  float* co = (float*)alloc((size_t)32*132*4);
  float* Y = (float*)L; // alias: Y dead before L written (25.2MB <= 33.5MB)

  float* outAs = out + NB*257;
  float* outAc = out + NB*257 + NB*NN;

  k_p2l<<<8192, 256, 0, stream>>>(srep, crep, lsb, lcb, lst, lct);
  k_prepW<<<dim3(128,3), 128, 0, stream>>>(Wl_w, Ws_w, Wc_w, Wb, Wt);
  k_lin<<<dim3(256,3), 256, 0, stream>>>(lsb, lcb, lst, lct, Wb, Wt, Wl_b, Ws_b, Wc_b, Y);
  k_post<<<3*16384, 128, 0, stream>>>(lsb, lcb, lst, lct, Wl_w, Ws_w, Wc_w,
                                      Wl_b, Ws_b, Wc_b, Wl_s, Ws_s, Wc_s,
                                      Y, Lwb, Lwt, Psb, Pcb);
  k_trP<<<dim3(8,16,2), 256, 0, stream>>>(Psb, Pcb, PsT, PcT);
  k_g1<<<2048, 256, 0, stream>>>(lsb, lst, Lwb, Lwt, L, LT, Tpart);
  k_Lfix<<<64, 256, 0, stream>>>(Tpart, L, LT, Ln);
  k_LTn<<<4096, 256, 0, stream>>>(LT, LTn);
  k_mx<<<dim3(256,2), 256, 0, stream>>>(L, LT, PcT, PsT, mxs, mxc);
  k_epi<<<2*16384, 128, 0, stream>>>(mxs, mxc, Psb, Pcb, Ln, LTn, whs, whc, logit);
  k_softmax<<<32, 256, 0, stream>>>(logit, outAs, outAc);
  k_cpart<<<dim3(8,16,2), 256, 0, stream>>>(outAs, outAc, lsb, lcb, lst, lct, part);
  k_cfin<<<32, 256, 0, stream>>>(part, co);
  k_final<<<16, 256, 0, stream>>>(co, out);
}

// Round 3
// 135.067 us; speedup vs baseline: 5.7275x; 1.2470x over previous
//
#include <hip/hip_runtime.h>

#define NN 1024
#define NB 16
#define SQRTK 11.313708498984761f

typedef float f32x4 __attribute__((ext_vector_type(4)));
typedef short bf16x8 __attribute__((ext_vector_type(8)));
typedef unsigned short ushort_t;
typedef unsigned int uint_t;

__device__ __forceinline__ ushort_t f2bf(float f){
  uint_t u = __float_as_uint(f);
  u += 0x7fffu + ((u>>16)&1u);
  return (ushort_t)(u>>16);
}
__device__ __forceinline__ float bf2f(ushort_t h){ return __uint_as_float(((uint_t)h)<<16); }

__device__ __forceinline__ float fast_tanh(float x){
  x = fminf(fmaxf(x,-15.f),15.f);
  float e = __expf(2.f*x);
  return (e-1.f)/(e+1.f);
}

__device__ __forceinline__ float artanh_clip(float x){
  x = fminf(fmaxf(x, -1.0f+1e-5f), 1.0f-1e-5f);
  return 0.5f*__logf((1.0f+x)/(1.0f-x));
}

// Stage nrows rows of 256B (128 bf16) each from row-strided global into LDS.
// LDS layout: byte(r, slot) = r*256 + (slot ^ (r&7))*16  (slot = 16B unit).
__device__ __forceinline__ void stage_swz(const ushort_t* __restrict__ g, int row_stride,
                                          char* ldsbase, int nrows, int tid){
  int lane = tid & 63;
  int w = tid >> 6;
  int ninst = nrows >> 2;
  int r_in = lane >> 4;
  int s_in = lane & 15;
  for (int inst = w; inst < ninst; inst += 4){
    int r = (inst<<2) + r_in;
    int s = s_in ^ (r & 7);
    const ushort_t* src = g + (size_t)r*row_stride + (s<<3);
    int instU = __builtin_amdgcn_readfirstlane(inst);
    __builtin_amdgcn_global_load_lds((const __attribute__((address_space(1))) void*)src,
        (__attribute__((address_space(3))) void*)(ldsbase + (instU<<10)), 16, 0, 0);
  }
}

__device__ __forceinline__ bf16x8 ldsfrag(const char* base, int r, int slot){
  return *(const bf16x8*)(base + ((r<<8) + ((slot ^ (r&7))<<4)));
}

// ---------------- K1: p2l -> bf16 space + fp32 time ----------------
__global__ void k_p2l(const float* __restrict__ S, const float* __restrict__ C,
                      ushort_t* __restrict__ lsb, ushort_t* __restrict__ lcb,
                      float* __restrict__ lst, float* __restrict__ lct){
  int gr = (blockIdx.x<<2) + (threadIdx.x>>6);
  int lane = threadIdx.x & 63;
  const float* in; ushort_t* ob; float* ot;
  if (gr < (NB<<10)){ in = S + (size_t)gr*128; ob = lsb + (size_t)gr*128; ot = lst+gr; }
  else { int r = gr - (NB<<10); in = C + (size_t)r*128; ob = lcb + (size_t)r*128; ot = lct+r; }
  float2 v = ((const float2*)in)[lane];
  float sq = v.x*v.x + v.y*v.y;
  #pragma unroll
  for (int o=32;o>0;o>>=1) sq += __shfl_xor(sq, o, 64);
  float inv = SQRTK/(1.f - sq + 1e-6f);
  uint_t pack = (uint_t)f2bf(2.f*v.x*inv) | ((uint_t)f2bf(2.f*v.y*inv)<<16);
  ((uint_t*)ob)[lane] = pack;
  if (lane==0) *ot = (1.f+sq)*inv;
}

// ---------------- K2: weight prep (bf16 space part + fp32 time col) ----------------
__global__ void k_prepW(const float* __restrict__ Wl, const float* __restrict__ Ws,
                        const float* __restrict__ Wc, ushort_t* __restrict__ Wb,
                        float* __restrict__ Wt){
  int j = blockIdx.x, w = blockIdx.y, t = threadIdx.x; // 128 threads
  const float* W = (w==0)? Wl : (w==1? Ws : Wc);
  Wb[((size_t)w<<14) + (j<<7) + t] = f2bf(W[j*129 + 1 + t]);
  if (t==0) Wt[(w<<7)+j] = W[j*129];
}

// ---------------- K3: Y = X@W.T (cols 0..127) via MFMA + rank-1 ----------------
__global__ __launch_bounds__(256) void k_lin(const ushort_t* __restrict__ lsb,
    const ushort_t* __restrict__ lcb, const float* __restrict__ lst, const float* __restrict__ lct,
    const ushort_t* __restrict__ Wb, const float* __restrict__ Wt,
    const float* __restrict__ bl, const float* __restrict__ bs, const float* __restrict__ bc,
    float* __restrict__ Y){
  __shared__ __attribute__((aligned(1024))) char sm[48*1024];
  int which = blockIdx.y;
  int m0 = blockIdx.x << 6;
  const ushort_t* A = ((which==1)? lsb : lcb) + (size_t)m0*128;
  const float* At = ((which==1)? lst : lct) + m0;
  const ushort_t* B = Wb + ((size_t)which<<14);
  const float* bias = (which==0)? bl : (which==1? bs : bc);
  float* Yw = Y + (((size_t)which<<14) + m0)*128;
  int tid = threadIdx.x, lane = tid&63;
  int w = tid>>6, wr = w>>1, wc = w&1, lo = lane&15, hi = lane>>4;
  f32x4 acc[2][4];
  #pragma unroll
  for (int i=0;i<2;i++)
    #pragma unroll
    for (int q=0;q<4;q++) acc[i][q] = (f32x4){0.f,0.f,0.f,0.f};
  char* Al = sm; char* Bl = sm + 16*1024;
  stage_swz(A, 128, Al, 64, tid);
  stage_swz(B, 128, Bl, 128, tid);
  __syncthreads();
  #pragma unroll
  for (int kc=0; kc<4; ++kc){
    bf16x8 av[2], bv[4];
    #pragma unroll
    for (int i=0;i<2;i++) av[i] = ldsfrag(Al, (wr<<5)+(i<<4)+lo, (kc<<2)+hi);
    #pragma unroll
    for (int q=0;q<4;q++) bv[q] = ldsfrag(Bl, (wc<<6)+(q<<4)+lo, (kc<<2)+hi);
    #pragma unroll
    for (int i=0;i<2;i++)
      #pragma unroll
      for (int q=0;q<4;q++)
        acc[i][q] = __builtin_amdgcn_mfma_f32_16x16x32_bf16(av[i], bv[q], acc[i][q], 0,0,0);
  }
  #pragma unroll
  for (int i=0;i<2;i++)
    #pragma unroll
    for (int q=0;q<4;q++)
      #pragma unroll
      for (int j=0;j<4;j++){
        int rl = (wr<<5)+(i<<4)+(hi<<2)+j;
        int cl = (wc<<6)+(q<<4)+lo;
        Yw[(size_t)rl*128 + cl] = acc[i][q][j] + At[rl]*Wt[(which<<7)+cl] + bias[cl];
      }
}

// ---------------- K4: lorentz_linear nonlinearity (wave per row) ----------------
__global__ __launch_bounds__(256) void k_post(const ushort_t* __restrict__ lsb,
    const ushort_t* __restrict__ lcb,
    const float* __restrict__ lst, const float* __restrict__ lct,
    const float* __restrict__ Wl, const float* __restrict__ Ws, const float* __restrict__ Wc,
    const float* __restrict__ bl, const float* __restrict__ bs, const float* __restrict__ bc,
    const float* __restrict__ scl, const float* __restrict__ scs, const float* __restrict__ scc,
    const float* __restrict__ Y, ushort_t* __restrict__ Lwb, float* __restrict__ Lwt,
    ushort_t* __restrict__ Psb, ushort_t* __restrict__ Pcb){
  int wid = threadIdx.x >> 6, lane = threadIdx.x & 63;
  int gr = (blockIdx.x << 2) + wid;       // 0..49151
  int which = gr >> 14, row = gr & 16383;
  const ushort_t* Xb = (which==1)? lsb : lcb;
  const float* Xt = (which==1)? lst : lct;
  const float* W = (which==0)? Wl : (which==1? Ws : Wc);
  const float* bias = (which==0)? bl : (which==1? bs : bc);
  float scale = __expf((which==0)? *scl : (which==1? *scs : *scc));
  const float* Yr = Y + ((size_t)gr)*128;
  // y128 = dot(X[row], W[128]) + b[128]
  uint_t xu = ((const uint_t*)(Xb + (size_t)row*128))[lane];
  float xa0 = bf2f((ushort_t)(xu & 0xffffu));
  float xa1 = bf2f((ushort_t)(xu >> 16));
  float w0 = W[128*129 + 1 + 2*lane];
  float w1 = W[128*129 + 2 + 2*lane];
  float pv = xa0*w0 + xa1*w1;
  if (lane==0) pv += Xt[row]*W[128*129];
  #pragma unroll
  for (int o=32;o>0;o>>=1) pv += __shfl_xor(pv,o,64);
  float y128 = pv + bias[128];
  // load Y row (elements j=2*lane, 2*lane+1)
  float2 yv = ((const float2*)Yr)[lane];
  float s2p = yv.y*yv.y + ((lane==0)? y128*y128 : yv.x*yv.x);
  #pragma unroll
  for (int o=32;o>0;o>>=1) s2p += __shfl_xor(s2p,o,64);
  float s2 = fmaxf(s2p, 1e-8f);
  float y0 = __shfl(yv.x, 0, 64);
  float time = scale/(1.f+__expf(-y0)) + 1.1f;
  float fac = sqrtf((time*time-1.f)/s2);
  // shifted store: out[2l] = y(2l+1)*f ; out[2l+1] = (l<63 ? y(2l+2) : y128)*f
  float nxt = __shfl_down(yv.x, 1, 64);
  if (lane==63) nxt = y128;
  if (which==0){
    uint_t pack = (uint_t)f2bf(yv.y*fac) | ((uint_t)f2bf(nxt*fac)<<16);
    ((uint_t*)(Lwb + (size_t)row*128))[lane] = pack;
    if (lane==0) Lwt[row] = time;
  } else {
    float iv = fac/(time + SQRTK);
    uint_t pack = (uint_t)f2bf(yv.y*iv) | ((uint_t)f2bf(nxt*iv)<<16);
    ushort_t* outp = ((which==1)? Psb : Pcb) + (size_t)row*128;
    ((uint_t*)outp)[lane] = pack;
  }
}

// ---------------- K5: transpose Ps/Pc -> PsT/PcT (bf16, [k][n]) ----------------
__global__ void k_trP(const ushort_t* __restrict__ Psb, const ushort_t* __restrict__ Pcb,
                      ushort_t* __restrict__ PsT, ushort_t* __restrict__ PcT){
  __shared__ ushort_t sm[128][136];
  int nt = blockIdx.x, b = blockIdx.y, which = blockIdx.z;
  const ushort_t* src = (which? Pcb : Psb) + (((size_t)(b<<10)) + (nt<<7))*128;
  ushort_t* dst = (which? PcT : PsT) + ((size_t)b<<17) + (nt<<7);
  int tid = threadIdx.x;
  for (int idx = tid; idx < 2048; idx += 256){
    int n = idx >> 4, sl = idx & 15;
    bf16x8 v = *(const bf16x8*)(src + (size_t)n*128 + (sl<<3));
    #pragma unroll
    for (int e=0;e<8;e++) sm[(sl<<3)+e][n] = (ushort_t)v[e];
  }
  __syncthreads();
  for (int idx = tid; idx < 2048; idx += 256){
    int k = idx >> 4, sl = idx & 15;
    bf16x8 v = *(const bf16x8*)(&sm[k][sl<<3]);
    *(bf16x8*)(dst + (size_t)k*NN + (sl<<3)) = v;
  }
}

// ---------------- K6: L = tanh(ls.Lw^T) bf16, + L^T, + row-sum partials ----------------
__global__ __launch_bounds__(256) void k_g1(const ushort_t* __restrict__ lsb,
    const float* __restrict__ lst, const ushort_t* __restrict__ Lwb, const float* __restrict__ Lwt,
    ushort_t* __restrict__ L, ushort_t* __restrict__ LT, float* __restrict__ Tpart){
  __shared__ __attribute__((aligned(1024))) char sm[48*1024];
  __shared__ float red[64][33];
  int bid = blockIdx.x;
  int ct = bid & 7, st = (bid>>3)&15, b = bid>>7;
  int s0 = st<<6, c0 = ct<<7;
  const ushort_t* A = lsb + ((size_t)(b<<10)+s0)*128;
  const ushort_t* Bm = Lwb + ((size_t)(b<<10)+c0)*128;
  int tid=threadIdx.x, lane=tid&63;
  int w=tid>>6, wr=w>>1, wc=w&1, lo=lane&15, hi=lane>>4;
  f32x4 acc[2][4];
  #pragma unroll
  for (int i=0;i<2;i++)
    #pragma unroll
    for (int q=0;q<4;q++) acc[i][q] = (f32x4){0.f,0.f,0.f,0.f};
  char* Al = sm; char* Bl = sm + 16*1024;
  stage_swz(A, 128, Al, 64, tid);
  stage_swz(Bm, 128, Bl, 128, tid);
  __syncthreads();
  #pragma unroll
  for (int kc=0; kc<4; ++kc){
    bf16x8 av[2], bv[4];
    #pragma unroll
    for (int i=0;i<2;i++) av[i] = ldsfrag(Al, (wr<<5)+(i<<4)+lo, (kc<<2)+hi);
    #pragma unroll
    for (int q=0;q<4;q++) bv[q] = ldsfrag(Bl, (wc<<6)+(q<<4)+lo, (kc<<2)+hi);
    #pragma unroll
    for (int i=0;i<2;i++)
      #pragma unroll
      for (int q=0;q<4;q++)
        acc[i][q] = __builtin_amdgcn_mfma_f32_16x16x32_bf16(av[i], bv[q], acc[i][q], 0,0,0);
  }
  float lwt4[4], lts[2][4];
  #pragma unroll
  for (int q=0;q<4;q++) lwt4[q] = Lwt[(b<<10)+c0+(wc<<6)+(q<<4)+lo];
  #pragma unroll
  for (int i=0;i<2;i++)
    #pragma unroll
    for (int j=0;j<4;j++) lts[i][j] = lst[(b<<10)+s0+(wr<<5)+(i<<4)+(hi<<2)+j];
  float p[2][4] = {};
  #pragma unroll
  for (int i=0;i<2;i++)
    #pragma unroll
    for (int q=0;q<4;q++)
      #pragma unroll
      for (int j=0;j<4;j++){
        float d = acc[i][q][j] + lts[i][j]*lwt4[q];
        float vv = fast_tanh(d);
        int rl = (wr<<5)+(i<<4)+(hi<<2)+j;
        int cl = (wc<<6)+(q<<4)+lo;
        size_t gs = (size_t)(b<<10)+s0+rl;
        size_t gc = (size_t)(b<<10)+c0+cl;
        L[gs*NN + c0+cl] = f2bf(vv);
        LT[gc*NN + s0+rl] = f2bf(vv);
        if (c0+cl != 0) p[i][j] += vv*vv;
      }
  #pragma unroll
  for (int i=0;i<2;i++)
    #pragma unroll
    for (int j=0;j<4;j++) red[(wr<<5)+(i<<4)+(hi<<2)+j][lo+(wc<<4)] = p[i][j];
  __syncthreads();
  if (tid < 64){
    float T=0.f;
    #pragma unroll
    for (int cc=0;cc<32;cc++) T += red[tid][cc];
    Tpart[((size_t)ct<<14) + (b<<10)+s0+tid] = T;
  }
}

// ---------------- K7: fix L[:, :, 0], LT[:, 0, :], Ln ----------------
__global__ void k_Lfix(const float* __restrict__ Tpart, ushort_t* __restrict__ L,
                       ushort_t* __restrict__ LT, float* __restrict__ Ln){
  int sg = blockIdx.x*256 + threadIdx.x; // 0..16383
  float T = 0.f;
  #pragma unroll
  for (int ct=0; ct<8; ++ct) T += Tpart[((size_t)ct<<14) + sg];
  float timev = sqrtf(1.f + T);
  int b = sg >> 10, s = sg & 1023;
  L[(size_t)sg*NN] = f2bf(timev);
  LT[((size_t)(b<<10))*NN + s] = f2bf(timev);
  Ln[sg] = sqrtf(1.f + 2.f*T);
}

// ---------------- K8: LTn (column norms of L = row norms of LT) ----------------
__global__ void k_LTn(const ushort_t* __restrict__ LT, float* __restrict__ LTn){
  int cg = (blockIdx.x<<2) + (threadIdx.x>>6);
  int lane = threadIdx.x & 63;
  const ushort_t* row = LT + (size_t)cg*NN + (lane<<4);
  float s = 0.f;
  #pragma unroll
  for (int h=0; h<2; ++h){
    bf16x8 vv = *(const bf16x8*)(row + (h<<3));
    #pragma unroll
    for (int e=0;e<8;e++){ float f = bf2f((ushort_t)vv[e]); s += f*f; }
  }
  #pragma unroll
  for (int o=32;o>0;o>>=1) s += __shfl_xor(s, o, 64);
  if (lane==0) LTn[cg] = fmaxf(sqrtf(s), 1e-15f);
}

// ---------------- K9: mxs = L@PcT^T ; mxc = LT@PsT^T ----------------
__global__ __launch_bounds__(256) void k_mx(const ushort_t* __restrict__ L,
    const ushort_t* __restrict__ LT, const ushort_t* __restrict__ PcT,
    const ushort_t* __restrict__ PsT, float* __restrict__ mxs, float* __restrict__ mxc){
  __shared__ __attribute__((aligned(1024))) char sm[48*1024];
  int side = blockIdx.y;
  int b = blockIdx.x >> 4;
  int m0 = (blockIdx.x & 15) << 6;
  const ushort_t* A = (side? LT : L) + ((size_t)(b<<10) + m0)*NN;
  const ushort_t* B = (side? PsT : PcT) + ((size_t)b<<17);
  float* C = (side? mxc : mxs) + ((size_t)(b<<10) + m0)*128;
  int tid = threadIdx.x, lane = tid&63;
  int w = tid>>6, wr = w>>1, wc = w&1, lo = lane&15, hi = lane>>4;
  f32x4 acc[2][4];
  #pragma unroll
  for (int i=0;i<2;i++)
    #pragma unroll
    for (int q=0;q<4;q++) acc[i][q] = (f32x4){0.f,0.f,0.f,0.f};
  char* Al = sm; char* Bl = sm + 16*1024;
  for (int ch=0; ch<8; ++ch){
    __syncthreads();
    stage_swz(A + (ch<<7), NN, Al, 64, tid);
    stage_swz(B + (ch<<7), NN, Bl, 128, tid);
    __syncthreads();
    #pragma unroll
    for (int kc=0; kc<4; ++kc){
      bf16x8 av[2], bv[4];
      #pragma unroll
      for (int i=0;i<2;i++) av[i] = ldsfrag(Al, (wr<<5)+(i<<4)+lo, (kc<<2)+hi);
      #pragma unroll
      for (int q=0;q<4;q++) bv[q] = ldsfrag(Bl, (wc<<6)+(q<<4)+lo, (kc<<2)+hi);
      #pragma unroll
      for (int i=0;i<2;i++)
        #pragma unroll
        for (int q=0;q<4;q++)
          acc[i][q] = __builtin_amdgcn_mfma_f32_16x16x32_bf16(av[i], bv[q], acc[i][q], 0,0,0);
    }
  }
  #pragma unroll
  for (int i=0;i<2;i++)
    #pragma unroll
    for (int q=0;q<4;q++)
      #pragma unroll
      for (int j=0;j<4;j++){
        int rl = (wr<<5)+(i<<4)+(hi<<2)+j;
        int cl = (wc<<6)+(q<<4)+lo;
        C[(size_t)rl*128 + cl] = acc[i][q][j];
      }
}

// ---------------- K10: fused Mobius/Lorentz epilogue (wave per row) ----------------
__global__ __launch_bounds__(256) void k_epi(const float* __restrict__ mxs,
    const float* __restrict__ mxc,
    const ushort_t* __restrict__ Psb, const ushort_t* __restrict__ Pcb,
    const float* __restrict__ Ln, const float* __restrict__ LTn,
    const float* __restrict__ whs, const float* __restrict__ whc, float* __restrict__ logit){
  int wid = threadIdx.x >> 6, lane = threadIdx.x & 63;
  int gr = (blockIdx.x << 2) + wid;       // 0..32767
  int side = gr >> 14, row = gr & 16383;
  const float* mx = (side? mxc : mxs) + (size_t)row*128;
  const ushort_t* xP = (side? Pcb : Psb) + (size_t)row*128;
  float xn = (side? LTn : Ln)[row];
  const float* wh = side? whc : whs;
  float2 mv = ((const float2*)mx)[lane];
  uint_t xu = ((const uint_t*)xP)[lane];
  float x0 = bf2f((ushort_t)(xu & 0xffffu));
  float x1 = bf2f((ushort_t)(xu >> 16));
  // pass 1: Σmx², Σx², Σx·mx  (fused butterfly)
  float pa = mv.x*mv.x + mv.y*mv.y;
  float pb = x0*x0 + x1*x1;
  float pc = x0*mv.x + x1*mv.y;
  #pragma unroll
  for (int o=32;o>0;o>>=1){
    pa += __shfl_xor(pa,o,64);
    pb += __shfl_xor(pb,o,64);
    pc += __shfl_xor(pc,o,64);
  }
  float mxn = fmaxf(sqrtf(pa), 1e-15f);
  float at1 = artanh_clip(xn);
  float fac = fast_tanh(mxn/xn*at1)/mxn;
  float xy = fac*pc;
  float x2 = pb;
  float y2 = fac*fac*pa;
  float den = fmaxf(1.0f + 2.0f*xy + x2*y2, 1e-15f);
  float ca = (1.0f+2.0f*xy+y2)/den;
  float cb = (1.0f-x2)*fac/den;
  float ma0 = ca*x0 + cb*mv.x;
  float ma1 = ca*x1 + cb*mv.y;
  // pass 2: Σma²
  float pm = ma0*ma0 + ma1*ma1;
  #pragma unroll
  for (int o=32;o>0;o>>=1) pm += __shfl_xor(pm,o,64);
  float scal = SQRTK*2.0f/(1.0f - pm + 1e-6f);
  float h0 = fast_tanh(scal*ma0);
  float h1 = fast_tanh(scal*ma1);
  // pass 3: Σh², Σh·wh (fused)
  float wv0 = wh[1 + 2*lane];
  float wv1 = wh[2 + 2*lane];
  float ps = h0*h0 + h1*h1;
  float pd = h0*wv0 + h1*wv1;
  #pragma unroll
  for (int o=32;o>0;o>>=1){
    ps += __shfl_xor(ps,o,64);
    pd += __shfl_xor(pd,o,64);
  }
  float timev = sqrtf(1.0f + ps);
  float hn = fmaxf(sqrtf(1.0f + 2.0f*ps), 1e-15f);
  float dotv = pd + timev*wh[0];
  float at2 = artanh_clip(hn);
  float mn = fmaxf(fabsf(dotv), 1e-15f);
  float lg = fast_tanh(mn/hn*at2)*(dotv/mn);
  if (lane==0) logit[gr] = lg;
}

// ---------------- K11: softmax ----------------
__global__ void k_softmax(const float* __restrict__ logit,
                          float* __restrict__ outAs, float* __restrict__ outAc){
  __shared__ float red4[4];
  int side = blockIdx.x >> 4;
  int b = blockIdx.x & 15;
  const float* lg = logit + (side<<14) + (b<<10);
  float* out = (side? outAc : outAs) + (b<<10);
  int t = threadIdx.x; // 256
  float l[4]; float m = -1e30f;
  #pragma unroll
  for (int i=0;i<4;i++){ l[i] = lg[t+256*i]; m = fmaxf(m,l[i]); }
  #pragma unroll
  for (int o=32;o>0;o>>=1) m = fmaxf(m, __shfl_down(m,o,64));
  if ((t&63)==0) red4[t>>6]=m;
  __syncthreads();
  m = fmaxf(fmaxf(red4[0],red4[1]), fmaxf(red4[2],red4[3]));
  __syncthreads();
  float s = 0.f; float e[4];
  #pragma unroll
  for (int i=0;i<4;i++){ e[i] = __expf(l[i]-m); s += e[i]; }
  #pragma unroll
  for (int o=32;o>0;o>>=1) s += __shfl_down(s,o,64);
  if ((t&63)==0) red4[t>>6]=s;
  __syncthreads();
  s = red4[0]+red4[1]+red4[2]+red4[3];
  float invs = 1.0f/s;
  #pragma unroll
  for (int i=0;i<4;i++) out[t+256*i] = e[i]*invs;
}

// ---------------- K12: centroid partials ----------------
__global__ void k_cpart(const float* __restrict__ As0, const float* __restrict__ Ac0,
    const ushort_t* __restrict__ lsb, const ushort_t* __restrict__ lcb,
    const float* __restrict__ lst, const float* __restrict__ lct, float* __restrict__ part){
  __shared__ float Psh[128];
  int ch = blockIdx.x, b = blockIdx.y, side = blockIdx.z;
  const float* P = (side? Ac0 : As0) + (b<<10) + (ch<<7);
  const ushort_t* Xb = (side? lcb : lsb) + (((size_t)(b<<10)) + (ch<<7))*128;
  const float* Xt = (side? lct : lst) + (b<<10) + (ch<<7);
  int t = threadIdx.x; // 256
  if (t < 128) Psh[t] = P[t];
  __syncthreads();
  float acc = 0.f;
  if (t < 128){
    for (int n=0; n<128; ++n) acc += Psh[n]*bf2f(Xb[(size_t)n*128 + t]);
  } else if (t == 128){
    for (int n=0; n<128; ++n) acc += Psh[n]*Xt[n];
  }
  if (t <= 128) part[((((size_t)side<<4) + b)*8 + ch)*132 + t] = acc;
}

// ---------------- K13: centroid finalize ----------------
__global__ void k_cfin(const float* __restrict__ part, float* __restrict__ co){
  __shared__ float red4[4];
  __shared__ float t0sh;
  int sb = blockIdx.x; int t = threadIdx.x; // 256
  float a = 0.f;
  if (t <= 128){
    #pragma unroll
    for (int ch=0; ch<8; ++ch) a += part[((size_t)sb*8+ch)*132 + t];
  }
  float val = (t < 128)? a*a : 0.f;
  #pragma unroll
  for (int o=32;o>0;o>>=1) val += __shfl_down(val,o,64);
  if ((t&63)==0) red4[t>>6]=val;
  if (t==128) t0sh = a;
  __syncthreads();
  float S = red4[0]+red4[1]+red4[2]+red4[3];
  float timev = t0sh;
  float inner = S - timev*timev;
  float dn = sqrtf(fmaxf(fabsf(inner), 1e-8f));
  if (t < 128) co[(size_t)sb*132 + 1 + t] = a/dn;
  if (t == 128) co[(size_t)sb*132] = timev/dn;
}

// ---------------- K14: assemble co_sc ----------------
__global__ void k_final(const float* __restrict__ co, float* __restrict__ out){
  __shared__ float red4[4];
  int b = blockIdx.x, t = threadIdx.x; // 256
  float sp = (t<128)? co[(size_t)b*132 + 1 + t]
                    : co[(size_t)(16 + b)*132 + 1 + (t-128)];
  float v = sp*sp;
  #pragma unroll
  for (int o=32;o>0;o>>=1) v += __shfl_down(v,o,64);
  if ((t&63)==0) red4[t>>6]=v;
  __syncthreads();
  float S = red4[0]+red4[1]+red4[2]+red4[3];
  float* ob = out + (size_t)b*257;
  if (t==0) ob[0] = sqrtf(1.0f + S);
  ob[1+t] = sp;
}

extern "C" void kernel_launch(void* const* d_in, const int* in_sizes, int n_in,
                              void* d_out, int out_size, void* d_ws, size_t ws_size,
                              hipStream_t stream) {
  const float* srep = (const float*)d_in[0];
  const float* crep = (const float*)d_in[1];
  const float* Wl_w = (const float*)d_in[2];
  const float* Wl_b = (const float*)d_in[3];
  const float* Wl_s = (const float*)d_in[4];
  const float* Ws_w = (const float*)d_in[5];
  const float* Ws_b = (const float*)d_in[6];
  const float* Ws_s = (const float*)d_in[7];
  const float* Wc_w = (const float*)d_in[8];
  const float* Wc_b = (const float*)d_in[9];
  const float* Wc_s = (const float*)d_in[10];
  const float* whs  = (const float*)d_in[11];
  const float* whc  = (const float*)d_in[12];
  float* out = (float*)d_out;

  char* wsb = (char*)d_ws;
  size_t off = 0;
  auto alloc = [&](size_t n)->char*{ char* p = wsb + off; off += (n + 255) & ~(size_t)255; return p; };
  ushort_t* lsb = (ushort_t*)alloc((size_t)16384*128*2);
  ushort_t* lcb = (ushort_t*)alloc((size_t)16384*128*2);
  float* lst = (float*)alloc(16384*4);
  float* lct = (float*)alloc(16384*4);
  ushort_t* Wb = (ushort_t*)alloc((size_t)3*16384*2);
  float* Wt = (float*)alloc(3*128*4);
  ushort_t* Lwb = (ushort_t*)alloc((size_t)16384*128*2);
  float* Lwt = (float*)alloc(16384*4);
  ushort_t* Psb = (ushort_t*)alloc((size_t)16384*128*2);
  ushort_t* Pcb = (ushort_t*)alloc((size_t)16384*128*2);
  ushort_t* PsT = (ushort_t*)alloc((size_t)16*128*1024*2);
  ushort_t* PcT = (ushort_t*)alloc((size_t)16*128*1024*2);
  ushort_t* L  = (ushort_t*)alloc((size_t)16*1024*1024*2);
  ushort_t* LT = (ushort_t*)alloc((size_t)16*1024*1024*2);
  float* Tpart = (float*)alloc((size_t)8*16384*4);
  float* mxs = (float*)alloc((size_t)16384*128*4);
  float* mxc = (float*)alloc((size_t)16384*128*4);
  float* Ln = (float*)alloc(16384*4);
  float* LTn = (float*)alloc(16384*4);
  float* logit = (float*)alloc((size_t)2*16384*4);
  float* part = (float*)alloc((size_t)2*16*8*132*4);
  float* co = (float*)alloc((size_t)32*132*4);
  float* Y = (float*)L; // alias: Y dead before L written

  float* outAs = out + NB*257;
  float* outAc = out + NB*257 + NB*NN;

  k_p2l<<<8192, 256, 0, stream>>>(srep, crep, lsb, lcb, lst, lct);
  k_prepW<<<dim3(128,3), 128, 0, stream>>>(Wl_w, Ws_w, Wc_w, Wb, Wt);
  k_lin<<<dim3(256,3), 256, 0, stream>>>(lsb, lcb, lst, lct, Wb, Wt, Wl_b, Ws_b, Wc_b, Y);
  k_post<<<12288, 256, 0, stream>>>(lsb, lcb, lst, lct, Wl_w, Ws_w, Wc_w,
                                    Wl_b, Ws_b, Wc_b, Wl_s, Ws_s, Wc_s,
                                    Y, Lwb, Lwt, Psb, Pcb);
  k_trP<<<dim3(8,16,2), 256, 0, stream>>>(Psb, Pcb, PsT, PcT);
  k_g1<<<2048, 256, 0, stream>>>(lsb, lst, Lwb, Lwt, L, LT, Tpart);
  k_Lfix<<<64, 256, 0, stream>>>(Tpart, L, LT, Ln);
  k_LTn<<<4096, 256, 0, stream>>>(LT, LTn);
  k_mx<<<dim3(256,2), 256, 0, stream>>>(L, LT, PcT, PsT, mxs, mxc);
  k_epi<<<8192, 256, 0, stream>>>(mxs, mxc, Psb, Pcb, Ln, LTn, whs, whc, logit);
  k_softmax<<<32, 256, 0, stream>>>(logit, outAs, outAc);
  k_cpart<<<dim3(8,16,2), 256, 0, stream>>>(outAs, outAc, lsb, lcb, lst, lct, part);
  k_cfin<<<32, 256, 0, stream>>>(part, co);
  k_final<<<16, 256, 0, stream>>>(co, out);
}